// Round 1
// baseline (14176.550 us; speedup 1.0000x reference)
//
#include <hip/hip_runtime.h>
#include <hip/hip_bf16.h>
#include <math.h>

// Problem constants (from reference): NODE_DIM=3, EMBED=16.
#define ND 3
#define EM 16

__device__ __forceinline__ float sp(float x) {
    // jax.nn.softplus = logaddexp(x, 0) = max(x,0) + log1p(exp(-|x|))
    return fmaxf(x, 0.0f) + log1pf(expf(-fabsf(x)));
}

// Kernel 1: x0 = softplus(pos @ W_init + b_init); xw = x0 @ W_g1.
// Also zero-init accumulator s, and init deg=1 (self-loop weight), cnt=1 (self loop).
__global__ __launch_bounds__(256) void node_init(
    const float* __restrict__ pos,
    const float* __restrict__ W_init, const float* __restrict__ b_init,
    const float* __restrict__ W_g1,
    float* __restrict__ xw, float* __restrict__ sacc,
    float* __restrict__ deg, float* __restrict__ cnt, int N)
{
    __shared__ float sWi[ND * EM];
    __shared__ float sbi[EM];
    __shared__ float sW1[EM * EM];
    int t = threadIdx.x;
    if (t < ND * EM) sWi[t] = W_init[t];
    if (t < EM)      sbi[t] = b_init[t];
    sW1[t] = W_g1[t];  // blockDim == 256 == EM*EM
    __syncthreads();

    int n = blockIdx.x * 256 + t;
    if (n >= N) return;

    float p0 = pos[3 * (size_t)n + 0];
    float p1 = pos[3 * (size_t)n + 1];
    float p2 = pos[3 * (size_t)n + 2];

    float x0[EM];
#pragma unroll
    for (int j = 0; j < EM; j++) {
        float h = fmaf(p0, sWi[0 * EM + j],
                  fmaf(p1, sWi[1 * EM + j],
                  fmaf(p2, sWi[2 * EM + j], sbi[j])));
        x0[j] = sp(h);
    }
    float o[EM];
#pragma unroll
    for (int k = 0; k < EM; k++) {
        float a = 0.0f;
#pragma unroll
        for (int j = 0; j < EM; j++) a = fmaf(x0[j], sW1[j * EM + k], a);
        o[k] = a;
    }
    float4* xo = (float4*)(xw + (size_t)n * EM);
    float4* so = (float4*)(sacc + (size_t)n * EM);
#pragma unroll
    for (int q = 0; q < 4; q++) {
        xo[q] = make_float4(o[4*q+0], o[4*q+1], o[4*q+2], o[4*q+3]);
        so[q] = make_float4(0.f, 0.f, 0.f, 0.f);
    }
    deg[n] = 1.0f;  // self-loop weight
    cnt[n] = 1.0f;  // self-loop count
}

// Kernel 2: per-edge weighted degree + count accumulation.
__global__ __launch_bounds__(256) void edge_deg(
    const int* __restrict__ ei, const float* __restrict__ pos,
    float* __restrict__ deg, float* __restrict__ cnt, int E)
{
    int e = blockIdx.x * 256 + threadIdx.x;
    if (e >= E) return;
    int s = ei[e];
    int d = ei[(size_t)E + e];
    float dx = pos[3 * (size_t)s + 0] - pos[3 * (size_t)d + 0];
    float dy = pos[3 * (size_t)s + 1] - pos[3 * (size_t)d + 1];
    float dz = pos[3 * (size_t)s + 2] - pos[3 * (size_t)d + 2];
    float w = sqrtf(fmaf(dx, dx, fmaf(dy, dy, dz * dz)));
    unsafeAtomicAdd(&deg[d], w);
    unsafeAtomicAdd(&cnt[d], 1.0f);
}

// Kernel 3: deg -> rsqrt(deg) in place; cnt -> 1/cnt in place.
// deg >= 1 always (self loop), so the deg>0 branch of the reference is always taken.
__global__ __launch_bounds__(256) void node_norm(
    float* __restrict__ deg, float* __restrict__ cnt, int N)
{
    int n = blockIdx.x * 256 + threadIdx.x;
    if (n >= N) return;
    deg[n] = rsqrtf(deg[n]);
    cnt[n] = 1.0f / cnt[n];
}

// Kernel 4/6: per-edge message scatter: s[dst] += dinv[src]*w*dinv[dst] * xw[src]
__global__ __launch_bounds__(256) void edge_msg(
    const int* __restrict__ ei, const float* __restrict__ pos,
    const float* __restrict__ dinv, const float* __restrict__ xw,
    float* __restrict__ sacc, int E)
{
    int e = blockIdx.x * 256 + threadIdx.x;
    if (e >= E) return;
    int s = ei[e];
    int d = ei[(size_t)E + e];
    float dx = pos[3 * (size_t)s + 0] - pos[3 * (size_t)d + 0];
    float dy = pos[3 * (size_t)s + 1] - pos[3 * (size_t)d + 1];
    float dz = pos[3 * (size_t)s + 2] - pos[3 * (size_t)d + 2];
    float w = sqrtf(fmaf(dx, dx, fmaf(dy, dy, dz * dz)));
    float nrm = dinv[s] * w * dinv[d];
    if (nrm == 0.0f) return;  // w==0 (e.g. src==dst) contributes nothing
    const float4* xr = (const float4*)(xw + (size_t)s * EM);
    float* so = sacc + (size_t)d * EM;
#pragma unroll
    for (int q = 0; q < 4; q++) {
        float4 v = xr[q];
        unsafeAtomicAdd(so + 4*q + 0, nrm * v.x);
        unsafeAtomicAdd(so + 4*q + 1, nrm * v.y);
        unsafeAtomicAdd(so + 4*q + 2, nrm * v.z);
        unsafeAtomicAdd(so + 4*q + 3, nrm * v.w);
    }
}

// Kernel 5: finalize layer-1 mean conv, softplus, then xw <- x1 @ W_g2 (in place),
// and re-zero s for layer 2.
__global__ __launch_bounds__(256) void node_mid(
    const float* __restrict__ b_g1, const float* __restrict__ W_g2,
    float* __restrict__ xw, float* __restrict__ sacc,
    const float* __restrict__ dinv, const float* __restrict__ rcnt, int N)
{
    __shared__ float sb[EM];
    __shared__ float sW[EM * EM];
    int t = threadIdx.x;
    if (t < EM) sb[t] = b_g1[t];
    sW[t] = W_g2[t];
    __syncthreads();

    int n = blockIdx.x * 256 + t;
    if (n >= N) return;

    float di = dinv[n];
    float selfw = di * di;      // 1/deg : self-loop norm
    float rc = rcnt[n];

    float4* xp = (float4*)(xw + (size_t)n * EM);
    float4* spt = (float4*)(sacc + (size_t)n * EM);
    float x1[EM];
#pragma unroll
    for (int q = 0; q < 4; q++) {
        float4 xv = xp[q];
        float4 sv = spt[q];
        x1[4*q+0] = sp(fmaf(fmaf(selfw, xv.x, sv.x), rc, sb[4*q+0]));
        x1[4*q+1] = sp(fmaf(fmaf(selfw, xv.y, sv.y), rc, sb[4*q+1]));
        x1[4*q+2] = sp(fmaf(fmaf(selfw, xv.z, sv.z), rc, sb[4*q+2]));
        x1[4*q+3] = sp(fmaf(fmaf(selfw, xv.w, sv.w), rc, sb[4*q+3]));
    }
    float o[EM];
#pragma unroll
    for (int k = 0; k < EM; k++) {
        float a = 0.0f;
#pragma unroll
        for (int j = 0; j < EM; j++) a = fmaf(x1[j], sW[j * EM + k], a);
        o[k] = a;
    }
#pragma unroll
    for (int q = 0; q < 4; q++) {
        xp[q] = make_float4(o[4*q+0], o[4*q+1], o[4*q+2], o[4*q+3]);
        spt[q] = make_float4(0.f, 0.f, 0.f, 0.f);
    }
}

// Kernel 7: finalize layer 2, two dense heads, divide by per-node sigma.
// Node n of graph g=n/A, atom a=n%A -> flat sigma index g*A+a == n.
__global__ __launch_bounds__(256) void node_out(
    const float* __restrict__ b_g2,
    const float* __restrict__ W_p1, const float* __restrict__ b_p1,
    const float* __restrict__ W_p2, const float* __restrict__ b_p2,
    const float* __restrict__ sig,
    const float* __restrict__ xw, const float* __restrict__ sacc,
    const float* __restrict__ dinv, const float* __restrict__ rcnt,
    float* __restrict__ out, int N)
{
    __shared__ float sb2[EM];
    __shared__ float sP1[EM * EM];
    __shared__ float sbp1[EM];
    __shared__ float sP2[EM * ND];
    __shared__ float sbp2[ND];
    int t = threadIdx.x;
    if (t < EM)      sb2[t] = b_g2[t];
    sP1[t] = W_p1[t];
    if (t < EM)      sbp1[t] = b_p1[t];
    if (t < EM * ND) sP2[t] = W_p2[t];
    if (t < ND)      sbp2[t] = b_p2[t];
    __syncthreads();

    int n = blockIdx.x * 256 + t;
    if (n >= N) return;

    float di = dinv[n];
    float selfw = di * di;
    float rc = rcnt[n];

    const float4* xp = (const float4*)(xw + (size_t)n * EM);
    const float4* spt = (const float4*)(sacc + (size_t)n * EM);
    float x2[EM];
#pragma unroll
    for (int q = 0; q < 4; q++) {
        float4 xv = xp[q];
        float4 sv = spt[q];
        x2[4*q+0] = sp(fmaf(fmaf(selfw, xv.x, sv.x), rc, sb2[4*q+0]));
        x2[4*q+1] = sp(fmaf(fmaf(selfw, xv.y, sv.y), rc, sb2[4*q+1]));
        x2[4*q+2] = sp(fmaf(fmaf(selfw, xv.z, sv.z), rc, sb2[4*q+2]));
        x2[4*q+3] = sp(fmaf(fmaf(selfw, xv.w, sv.w), rc, sb2[4*q+3]));
    }
    float y[EM];
#pragma unroll
    for (int k = 0; k < EM; k++) {
        float a = sbp1[k];
#pragma unroll
        for (int j = 0; j < EM; j++) a = fmaf(x2[j], sP1[j * EM + k], a);
        y[k] = sp(a);
    }
    float rs = 1.0f / sig[n];
#pragma unroll
    for (int c = 0; c < ND; c++) {
        float a = sbp2[c];
#pragma unroll
        for (int j = 0; j < EM; j++) a = fmaf(y[j], sP2[j * ND + c], a);
        out[(size_t)n * ND + c] = a * rs;
    }
}

extern "C" void kernel_launch(void* const* d_in, const int* in_sizes, int n_in,
                              void* d_out, int out_size, void* d_ws, size_t ws_size,
                              hipStream_t stream) {
    const float* pos   = (const float*)d_in[0];
    const float* sig   = (const float*)d_in[1];
    const int*   ei    = (const int*)d_in[2];
    // d_in[3] = num_graphs (unused: flat sigma index == node index)
    const float* W_init = (const float*)d_in[4];
    const float* b_init = (const float*)d_in[5];
    const float* W_g1   = (const float*)d_in[6];
    const float* b_g1   = (const float*)d_in[7];
    const float* W_g2   = (const float*)d_in[8];
    const float* b_g2   = (const float*)d_in[9];
    const float* W_p1   = (const float*)d_in[10];
    const float* b_p1   = (const float*)d_in[11];
    const float* W_p2   = (const float*)d_in[12];
    const float* b_p2   = (const float*)d_in[13];
    float* out = (float*)d_out;

    int N = in_sizes[0] / ND;
    int E = in_sizes[2] / 2;

    // Workspace layout (floats): xw[N*16] | s[N*16] | deg/dinv[N] | cnt/rcnt[N]
    float* xw   = (float*)d_ws;
    float* sacc = xw + (size_t)N * EM;
    float* deg  = sacc + (size_t)N * EM;
    float* cnt  = deg + N;

    int nbN = (N + 255) / 256;
    int nbE = (E + 255) / 256;

    node_init<<<nbN, 256, 0, stream>>>(pos, W_init, b_init, W_g1, xw, sacc, deg, cnt, N);
    edge_deg<<<nbE, 256, 0, stream>>>(ei, pos, deg, cnt, E);
    node_norm<<<nbN, 256, 0, stream>>>(deg, cnt, N);
    edge_msg<<<nbE, 256, 0, stream>>>(ei, pos, deg /*=dinv*/, xw, sacc, E);
    node_mid<<<nbN, 256, 0, stream>>>(b_g1, W_g2, xw, sacc, deg, cnt, N);
    edge_msg<<<nbE, 256, 0, stream>>>(ei, pos, deg /*=dinv*/, xw, sacc, E);
    node_out<<<nbN, 256, 0, stream>>>(b_g2, W_p1, b_p1, W_p2, b_p2, sig,
                                      xw, sacc, deg, cnt, out, N);
}

// Round 2
// 1886.311 us; speedup vs baseline: 7.5155x; 7.5155x over previous
//
#include <hip/hip_runtime.h>
#include <hip/hip_bf16.h>
#include <math.h>

// NODE_DIM=3, EMBED=16
#define ND 3
#define EM 16

__device__ __forceinline__ float sp(float x) {
    // jax.nn.softplus = max(x,0) + log1p(exp(-|x|))
    return fmaxf(x, 0.0f) + log1pf(expf(-fabsf(x)));
}

// Kernel 1: x0 = softplus(pos @ W_init + b_init); xwA = x0 @ W_g1. Zero cnt.
__global__ __launch_bounds__(256) void node_init(
    const float* __restrict__ pos,
    const float* __restrict__ W_init, const float* __restrict__ b_init,
    const float* __restrict__ W_g1,
    float* __restrict__ xw, int* __restrict__ cnt, int N)
{
    __shared__ float sWi[ND * EM];
    __shared__ float sbi[EM];
    __shared__ float sW1[EM * EM];
    int t = threadIdx.x;
    if (t < ND * EM) sWi[t] = W_init[t];
    if (t < EM)      sbi[t] = b_init[t];
    sW1[t] = W_g1[t];
    __syncthreads();

    int n = blockIdx.x * 256 + t;
    if (n >= N) return;

    float p0 = pos[3 * (size_t)n + 0];
    float p1 = pos[3 * (size_t)n + 1];
    float p2 = pos[3 * (size_t)n + 2];

    float x0[EM];
#pragma unroll
    for (int j = 0; j < EM; j++) {
        float h = fmaf(p0, sWi[0 * EM + j],
                  fmaf(p1, sWi[1 * EM + j],
                  fmaf(p2, sWi[2 * EM + j], sbi[j])));
        x0[j] = sp(h);
    }
    float o[EM];
#pragma unroll
    for (int k = 0; k < EM; k++) {
        float a = 0.0f;
#pragma unroll
        for (int j = 0; j < EM; j++) a = fmaf(x0[j], sW1[j * EM + k], a);
        o[k] = a;
    }
    float4* xo = (float4*)(xw + (size_t)n * EM);
#pragma unroll
    for (int q = 0; q < 4; q++)
        xo[q] = make_float4(o[4*q+0], o[4*q+1], o[4*q+2], o[4*q+3]);
    cnt[n] = 0;
}

// Kernel 2: in-degree count (int atomics, L2-resident 2MB array).
__global__ __launch_bounds__(256) void edge_count(
    const int* __restrict__ ei, int* __restrict__ cnt, int E)
{
    int e = blockIdx.x * 256 + threadIdx.x;
    if (e >= E) return;
    int d = ei[(size_t)E + e];
    atomicAdd(&cnt[d], 1);
}

// Kernel 3a: per-block (1024 nodes) partial sums of cnt.
__global__ __launch_bounds__(256) void scan_partial(
    const int* __restrict__ cnt, int* __restrict__ bsums, int N)
{
    __shared__ int sd[256];
    int t = threadIdx.x;
    int base = blockIdx.x * 1024 + t * 4;
    int s = 0;
#pragma unroll
    for (int i = 0; i < 4; i++) { int n = base + i; if (n < N) s += cnt[n]; }
    sd[t] = s;
    __syncthreads();
    for (int off = 128; off >= 1; off >>= 1) {
        if (t < off) sd[t] += sd[t + off];
        __syncthreads();
    }
    if (t == 0) bsums[blockIdx.x] = sd[0];
}

// Kernel 3b: exclusive scan of block sums in place (NB <= 1024).
__global__ __launch_bounds__(1024) void scan_blocksums(int* __restrict__ bsums, int NB)
{
    __shared__ int sd[1024];
    int t = threadIdx.x;
    int v = (t < NB) ? bsums[t] : 0;
    sd[t] = v;
    __syncthreads();
    for (int off = 1; off < 1024; off <<= 1) {
        int add = (t >= off) ? sd[t - off] : 0;
        __syncthreads();
        sd[t] += add;
        __syncthreads();
    }
    if (t < NB) bsums[t] = sd[t] - v;  // exclusive
}

// Kernel 3c: final rowptr + cursor init.
__global__ __launch_bounds__(256) void scan_final(
    const int* __restrict__ cnt, const int* __restrict__ bsums,
    int* __restrict__ rowptr, int* __restrict__ cursor, int N, int E)
{
    __shared__ int sd[256];
    int t = threadIdx.x;
    int n0 = blockIdx.x * 1024 + t * 4;
    int c[4];
#pragma unroll
    for (int i = 0; i < 4; i++) c[i] = (n0 + i < N) ? cnt[n0 + i] : 0;
    int mysum = c[0] + c[1] + c[2] + c[3];
    sd[t] = mysum;
    __syncthreads();
    for (int off = 1; off < 256; off <<= 1) {
        int add = (t >= off) ? sd[t - off] : 0;
        __syncthreads();
        sd[t] += add;
        __syncthreads();
    }
    int r = bsums[blockIdx.x] + sd[t] - mysum;
#pragma unroll
    for (int i = 0; i < 4; i++) {
        int n = n0 + i;
        if (n < N) { rowptr[n] = r; cursor[n] = r; r += c[i]; }
    }
    if (blockIdx.x == 0 && t == 0) rowptr[N] = E;
}

// Kernel 4: scatter edge src ids into dst-sorted buckets.
__global__ __launch_bounds__(256) void edge_fill(
    const int* __restrict__ ei, int* __restrict__ cursor,
    int* __restrict__ col, int E)
{
    int e = blockIdx.x * 256 + threadIdx.x;
    if (e >= E) return;
    int s = ei[e];
    int d = ei[(size_t)E + e];
    int slot = atomicAdd(&cursor[d], 1);
    col[slot] = s;
}

// Kernel 5: weighted degree via gather; dinv = rsqrt(1 + sum_w).
// 16 lanes per node; lane j handles edges start+j, start+j+16, ...
__global__ __launch_bounds__(256) void deg_gather(
    const int* __restrict__ rowptr, const int* __restrict__ col,
    const float* __restrict__ pos, float* __restrict__ dinv, int N)
{
    int t = threadIdx.x;
    int lane = t & 15;
    int n = blockIdx.x * 16 + (t >> 4);
    if (n >= N) return;
    int start = rowptr[n], end = rowptr[n + 1];
    float px = pos[3 * (size_t)n + 0];
    float py = pos[3 * (size_t)n + 1];
    float pz = pos[3 * (size_t)n + 2];
    float sum = 0.0f;
    for (int j = start + lane; j < end; j += 16) {
        int s = col[j];
        float dx = px - pos[3 * (size_t)s + 0];
        float dy = py - pos[3 * (size_t)s + 1];
        float dz = pz - pos[3 * (size_t)s + 2];
        sum += sqrtf(fmaf(dx, dx, fmaf(dy, dy, dz * dz)));
    }
#pragma unroll
    for (int off = 8; off >= 1; off >>= 1) sum += __shfl_xor(sum, off, 64);
    if (lane == 0) dinv[n] = rsqrtf(1.0f + sum);
}

// Kernel 6 (x2): fused GCN-mean layer via gather.
// 16 lanes per node, lane = output channel. For each incident edge:
// nrm = dinv[src]*w*dinv[n]; acc += nrm * xin[src][c]. Then add self-loop
// dinv^2 * xin[n][c], divide by (deg_count+1), add bias, softplus.
// If mulW: out = x @ W (16x16) via LDS; else out = x.
__global__ __launch_bounds__(256) void gather_conv(
    const int* __restrict__ rowptr, const int* __restrict__ col,
    const float* __restrict__ pos, const float* __restrict__ dinv,
    const float* __restrict__ xin, const float* __restrict__ bconv,
    const float* __restrict__ W, float* __restrict__ xout, int N, int mulW)
{
    __shared__ float sW[EM * EM];
    __shared__ float lx[16][EM + 1];
    int t = threadIdx.x;
    sW[t] = W[t];
    int g = t >> 4, c = t & 15;
    int n = blockIdx.x * 16 + g;

    float x = 0.0f;
    if (n < N) {
        int start = rowptr[n], end = rowptr[n + 1];
        float di = dinv[n];
        float px = pos[3 * (size_t)n + 0];
        float py = pos[3 * (size_t)n + 1];
        float pz = pos[3 * (size_t)n + 2];
        float acc = 0.0f;
        for (int j = start; j < end; j++) {
            int s = col[j];
            float dx = px - pos[3 * (size_t)s + 0];
            float dy = py - pos[3 * (size_t)s + 1];
            float dz = pz - pos[3 * (size_t)s + 2];
            float w = sqrtf(fmaf(dx, dx, fmaf(dy, dy, dz * dz)));
            float nrm = dinv[s] * w * di;
            acc = fmaf(nrm, xin[(size_t)s * EM + c], acc);
        }
        acc = fmaf(di * di, xin[(size_t)n * EM + c], acc);  // self loop
        float rc = 1.0f / (float)(end - start + 1);
        x = sp(fmaf(acc, rc, bconv[c]));
    }
    __syncthreads();      // sW ready
    lx[g][c] = x;
    __syncthreads();
    if (n < N) {
        if (mulW) {
            float a = 0.0f;
#pragma unroll
            for (int j = 0; j < EM; j++) a = fmaf(lx[g][j], sW[j * EM + c], a);
            xout[(size_t)n * EM + c] = a;
        } else {
            xout[(size_t)n * EM + c] = x;
        }
    }
}

// Kernel 7: dense heads: y = sp(x2 @ Wp1 + bp1); out = (y @ Wp2 + bp2)/sig.
__global__ __launch_bounds__(256) void node_out(
    const float* __restrict__ W_p1, const float* __restrict__ b_p1,
    const float* __restrict__ W_p2, const float* __restrict__ b_p2,
    const float* __restrict__ sig, const float* __restrict__ x2arr,
    float* __restrict__ out, int N)
{
    __shared__ float sP1[EM * EM];
    __shared__ float sbp1[EM];
    __shared__ float sP2[EM * ND];
    __shared__ float sbp2[ND];
    int t = threadIdx.x;
    sP1[t] = W_p1[t];
    if (t < EM)      sbp1[t] = b_p1[t];
    if (t < EM * ND) sP2[t] = W_p2[t];
    if (t < ND)      sbp2[t] = b_p2[t];
    __syncthreads();

    int n = blockIdx.x * 256 + t;
    if (n >= N) return;

    const float4* xp = (const float4*)(x2arr + (size_t)n * EM);
    float x2[EM];
#pragma unroll
    for (int q = 0; q < 4; q++) {
        float4 xv = xp[q];
        x2[4*q+0] = xv.x; x2[4*q+1] = xv.y; x2[4*q+2] = xv.z; x2[4*q+3] = xv.w;
    }
    float y[EM];
#pragma unroll
    for (int k = 0; k < EM; k++) {
        float a = sbp1[k];
#pragma unroll
        for (int j = 0; j < EM; j++) a = fmaf(x2[j], sP1[j * EM + k], a);
        y[k] = sp(a);
    }
    float rs = 1.0f / sig[n];
#pragma unroll
    for (int ch = 0; ch < ND; ch++) {
        float a = sbp2[ch];
#pragma unroll
        for (int j = 0; j < EM; j++) a = fmaf(y[j], sP2[j * ND + ch], a);
        out[(size_t)n * ND + ch] = a * rs;
    }
}

extern "C" void kernel_launch(void* const* d_in, const int* in_sizes, int n_in,
                              void* d_out, int out_size, void* d_ws, size_t ws_size,
                              hipStream_t stream) {
    const float* pos    = (const float*)d_in[0];
    const float* sig    = (const float*)d_in[1];
    const int*   ei     = (const int*)d_in[2];
    const float* W_init = (const float*)d_in[4];
    const float* b_init = (const float*)d_in[5];
    const float* W_g1   = (const float*)d_in[6];
    const float* b_g1   = (const float*)d_in[7];
    const float* W_g2   = (const float*)d_in[8];
    const float* b_g2   = (const float*)d_in[9];
    const float* W_p1   = (const float*)d_in[10];
    const float* b_p1   = (const float*)d_in[11];
    const float* W_p2   = (const float*)d_in[12];
    const float* b_p2   = (const float*)d_in[13];
    float* out = (float*)d_out;

    int N = in_sizes[0] / ND;
    int E = in_sizes[2] / 2;
    size_t Ns = (size_t)N, Es = (size_t)E;

    // Workspace layout (4B elements):
    // rowptr[N+1] | cnt[N] | col[E] | bsums[1024] | dinv[N] | xwA[16N] | xwB[16N]
    // cursor aliases the start of xwB (dead before xwB is first written).
    int* rowptr = (int*)d_ws;
    int* cnt    = rowptr + (Ns + 1);
    int* col    = cnt + Ns;
    int* bsums  = col + Es;
    size_t off  = (Ns + 1) + Ns + Es + 1024;
    off = (off + 3) & ~(size_t)3;
    float* dinv = (float*)d_ws + off;
    size_t offA = off + Ns;
    offA = (offA + 3) & ~(size_t)3;
    float* xwA  = (float*)d_ws + offA;
    float* xwB  = xwA + Ns * EM;
    int* cursor = (int*)xwB;

    int nbN = (N + 255) / 256;
    int nbE = (E + 255) / 256;
    int NBS = (N + 1023) / 1024;   // scan blocks (must be <= 1024)
    int nbG = (N + 15) / 16;       // 16 nodes per 256-thread block

    node_init<<<nbN, 256, 0, stream>>>(pos, W_init, b_init, W_g1, xwA, cnt, N);
    edge_count<<<nbE, 256, 0, stream>>>(ei, cnt, E);
    scan_partial<<<NBS, 256, 0, stream>>>(cnt, bsums, N);
    scan_blocksums<<<1, 1024, 0, stream>>>(bsums, NBS);
    scan_final<<<NBS, 256, 0, stream>>>(cnt, bsums, rowptr, cursor, N, E);
    edge_fill<<<nbE, 256, 0, stream>>>(ei, cursor, col, E);
    deg_gather<<<nbG, 256, 0, stream>>>(rowptr, col, pos, dinv, N);
    gather_conv<<<nbG, 256, 0, stream>>>(rowptr, col, pos, dinv, xwA, b_g1, W_g2, xwB, N, 1);
    gather_conv<<<nbG, 256, 0, stream>>>(rowptr, col, pos, dinv, xwB, b_g2, W_g2, xwA, N, 0);
    node_out<<<nbN, 256, 0, stream>>>(W_p1, b_p1, W_p2, b_p2, sig, xwA, out, N);
}